// Round 4
// baseline (229.685 us; speedup 1.0000x reference)
//
#include <hip/hip_runtime.h>

// ---- problem constants (B,H0,W0,C)=(16,56,56,96), NH=3, WS=7, SS=3, HID=384, NCL=128 ----
#define NB 16
#define NHH 56
#define NWW 56
#define NC 96
#define NL (NHH*NWW)          // 3136
#define NTOK (NB*NL)          // 50176
#define WSZ 7
#define NT 49                 // tokens per window
#define SSH 3
#define NWIN 1024             // 16 * 8 * 8
#define HDIM 32
#define HID_ 384
#define NCL_ 128
#define NLIT 768
#define EPS_ 1e-6f
#define LOG_EPS -13.815510558f

typedef unsigned short u16;
typedef unsigned int   u32;
typedef __attribute__((ext_vector_type(8))) short short8;   // 8 bf16 (4 VGPRs)
typedef __attribute__((ext_vector_type(4))) float f32x4;    // MFMA C/D

__device__ __forceinline__ float us2f(u16 u) {
  union { u32 u; float f; } x; x.u = ((u32)u) << 16; return x.f;
}
__device__ __forceinline__ u16 f2us(float f) {   // RNE float->bf16
  union { float f; u32 u; } x; x.f = f;
  u32 lsb = (x.u >> 16) & 1u;
  return (u16)((x.u + 0x7fffu + lsb) >> 16);
}
__device__ __forceinline__ float sigmoidf_(float x) { return 1.f / (1.f + __expf(-x)); }

// ---------------- K0: build bf16 constants ----------------
// maskb is stored COLUMN-INTERLEAVED: permuted col q holds source literal
// j = (q&1) ? 384 + q/2 : q/2.  k4 produces literal pairs (a-sp, -sp) for
// hidden o as one u32 -> exactly cols (2o, 2o+1) of the clause A-frag.
__global__ __launch_bounds__(256) void k0_prep(const float* __restrict__ tm_inc,
                                               const float* __restrict__ pin_w,
                                               const float* __restrict__ tm_out,
                                               const float* __restrict__ qkv_w,
                                               const float* __restrict__ proj_w,
                                               u16* __restrict__ maskb,
                                               u16* __restrict__ pinwb,
                                               u16* __restrict__ tmoT,
                                               u16* __restrict__ qkvwb,
                                               u16* __restrict__ projwb) {
  int idx = blockIdx.x * 256 + threadIdx.x;
  if (idx < NCL_ * NLIT) {
    int c = idx / NLIT, q = idx - c * NLIT;
    int j = (q & 1) ? (q >> 1) + HID_ : (q >> 1);
    maskb[idx] = (tm_inc[(size_t)c * NLIT + j] > 0.f) ? (u16)0x3F80 : (u16)0;
  }
  if (idx < HID_ * NC)
    pinwb[idx] = f2us(pin_w[idx]);
  if (idx < NC * NCL_) {
    int c = idx / NCL_, k = idx - c * NCL_;
    tmoT[idx] = f2us(tm_out[(size_t)k * NC + c]);
  }
  if (idx < 3 * NC * NC)
    qkvwb[idx] = f2us(qkv_w[idx]);
  if (idx < NC * NC)
    projwb[idx] = f2us(proj_w[idx]);
}

// ---------------- K2: LN1 + window gather + MFMA attention + proj + residual scatter ----------------
// (unchanged from round 1)
__global__ __launch_bounds__(256, 4) void k2_attn(const float* __restrict__ x,
                                               const float* __restrict__ n1g,
                                               const float* __restrict__ n1b,
                                               const u16* __restrict__ qkvwb,
                                               const float* __restrict__ qkv_b,
                                               const u16* __restrict__ projwb,
                                               const float* __restrict__ proj_b,
                                               float* __restrict__ x1) {
  __shared__ __align__(16) u16 syb[64 * 104];
  __shared__ __align__(16) u16 sk [64 * 104];
  __shared__ __align__(16) u16 svT[96 * 72];
  const int tid  = threadIdx.x;
  const int wave = tid >> 6;
  const int lane = tid & 63;
  const int l16  = lane & 15;
  const int quad = lane >> 4;
  const int win  = blockIdx.x;
  const int t0   = wave * 16;
  const int bb = win >> 6, wl = win & 63;
  const int hbase = (wl >> 3) * WSZ, wbase = (wl & 7) * WSZ;

  // ---- LN1 head: 4 threads per token; gather from x with inverse global roll ----
  {
    const int t = tid >> 2, s = tid & 3;
    if (t < NT) {
      int hp = hbase + t / WSZ, wp = wbase + t % WSZ;
      int h = hp + SSH; if (h >= NHH) h -= NHH;
      int w = wp + SSH; if (w >= NWW) w -= NWW;
      const float* xp = x + ((size_t)bb * NL + (size_t)h * NWW + w) * NC;
      float4 v[6];
      float sum = 0.f;
      #pragma unroll
      for (int k = 0; k < 6; ++k) {
        v[k] = *reinterpret_cast<const float4*>(xp + s * 4 + k * 16);
        sum += v[k].x + v[k].y + v[k].z + v[k].w;
      }
      sum += __shfl_xor(sum, 1); sum += __shfl_xor(sum, 2);
      float mean = sum * (1.f / 96.f);
      float ssq = 0.f;
      #pragma unroll
      for (int k = 0; k < 6; ++k) {
        float d0 = v[k].x - mean, d1 = v[k].y - mean;
        float d2 = v[k].z - mean, d3 = v[k].w - mean;
        ssq += d0 * d0 + d1 * d1 + d2 * d2 + d3 * d3;
      }
      ssq += __shfl_xor(ssq, 1); ssq += __shfl_xor(ssq, 2);
      float rstd = rsqrtf(ssq * (1.f / 96.f) + 1e-5f);
      #pragma unroll
      for (int k = 0; k < 6; ++k) {
        int c = s * 4 + k * 16;
        const float4 g4 = *reinterpret_cast<const float4*>(n1g + c);
        const float4 b4 = *reinterpret_cast<const float4*>(n1b + c);
        syb[t * 104 + c + 0] = f2us((v[k].x - mean) * rstd * g4.x + b4.x);
        syb[t * 104 + c + 1] = f2us((v[k].y - mean) * rstd * g4.y + b4.y);
        syb[t * 104 + c + 2] = f2us((v[k].z - mean) * rstd * g4.z + b4.z);
        syb[t * 104 + c + 3] = f2us((v[k].w - mean) * rstd * g4.w + b4.w);
      }
    } else {
      #pragma unroll
      for (int k = 0; k < 6; ++k) {
        int c = s * 4 + k * 16;
        syb[t * 104 + c + 0] = 0; syb[t * 104 + c + 1] = 0;
        syb[t * 104 + c + 2] = 0; syb[t * 104 + c + 3] = 0;
      }
    }
  }
  // NO __syncthreads() here: A-frag rows below are wave-own.

  // ---- QKV: M=64, N=288 (18 tiles), K=96 (3 steps); depth-4 B-frag ring. ----
  {
    short8 afr[3];
    #pragma unroll
    for (int ks = 0; ks < 3; ++ks)
      afr[ks] = *reinterpret_cast<const short8*>(&syb[(t0 + l16) * 104 + quad * 8 + ks * 32]);
    short8 rb[4][3];
    #pragma unroll
    for (int p = 0; p < 4; ++p)
      #pragma unroll
      for (int ks = 0; ks < 3; ++ks)
        rb[p][ks] = *reinterpret_cast<const short8*>(
            qkvwb + (size_t)(p * 16 + l16) * NC + quad * 8 + ks * 32);
    #pragma unroll
    for (int nt = 0; nt < 18; ++nt) {
      const int n0 = nt * 16;
      const float bias = qkv_b[n0 + l16];
      short8 b0 = rb[nt & 3][0], b1 = rb[nt & 3][1], b2 = rb[nt & 3][2];
      if (nt + 4 < 18) {
        #pragma unroll
        for (int ks = 0; ks < 3; ++ks)
          rb[nt & 3][ks] = *reinterpret_cast<const short8*>(
              qkvwb + (size_t)((nt + 4) * 16 + l16) * NC + quad * 8 + ks * 32);
      }
      f32x4 acc = {0.f, 0.f, 0.f, 0.f};
      acc = __builtin_amdgcn_mfma_f32_16x16x32_bf16(afr[0], b0, acc, 0, 0, 0);
      acc = __builtin_amdgcn_mfma_f32_16x16x32_bf16(afr[1], b1, acc, 0, 0, 0);
      acc = __builtin_amdgcn_mfma_f32_16x16x32_bf16(afr[2], b2, acc, 0, 0, 0);
      const int part = nt / 6;                 // 0=q 1=k 2=v
      const int oc = n0 - part * 96 + l16;
      if (part < 2) {
        u16* dst = (part == 0) ? syb : sk;     // q overwrites y in wave-own rows
        #pragma unroll
        for (int r = 0; r < 4; ++r)
          dst[(t0 + quad * 4 + r) * 104 + oc] = f2us(acc[r] + bias);
      } else {
        #pragma unroll
        for (int r = 0; r < 4; ++r)
          svT[oc * 72 + (t0 + quad * 4 + r)] = f2us(acc[r] + bias);
      }
    }
  }
  __syncthreads();   // B2: k/v (cross-wave) must be complete

  // ---- all-head scores first, then per-head softmax+PV ----
  u16* spw = sk + wave * 16 * 72;              // sp ALIASES sk (sk dead after score phase)
  const float sscale = 0.17677669529663687f;
  short8 qf[3];
  f32x4 s[3][4];
  #pragma unroll
  for (int h = 0; h < 3; ++h)
    qf[h] = *reinterpret_cast<const short8*>(&syb[(t0 + l16) * 104 + h * HDIM + quad * 8]);
  #pragma unroll
  for (int h = 0; h < 3; ++h) {
    const int d0 = h * HDIM;
    #pragma unroll
    for (int nt = 0; nt < 4; ++nt) {
      short8 kf = *reinterpret_cast<const short8*>(&sk[(nt * 16 + l16) * 104 + d0 + quad * 8]);
      f32x4 a = {0.f, 0.f, 0.f, 0.f};
      s[h][nt] = __builtin_amdgcn_mfma_f32_16x16x32_bf16(qf[h], kf, a, 0, 0, 0);
    }
  }
  __syncthreads();   // B3s: all sk reads complete before spw (sk-alias) writes
  #pragma unroll
  for (int h = 0; h < 3; ++h) {
    const int d0 = h * HDIM;
    #pragma unroll
    for (int nt = 0; nt < 4; ++nt)
      #pragma unroll
      for (int r = 0; r < 4; ++r) s[h][nt][r] *= sscale;
    if (l16 >= 1) {                       // key col 48+l16 >= 49 -> mask
      #pragma unroll
      for (int r = 0; r < 4; ++r) s[h][3][r] = -1e30f;
    }
    #pragma unroll
    for (int r = 0; r < 4; ++r) {
      float m = fmaxf(fmaxf(s[h][0][r], s[h][1][r]), fmaxf(s[h][2][r], s[h][3][r]));
      #pragma unroll
      for (int off = 8; off > 0; off >>= 1) m = fmaxf(m, __shfl_xor(m, off, 16));
      float e0 = __expf(s[h][0][r] - m), e1 = __expf(s[h][1][r] - m);
      float e2 = __expf(s[h][2][r] - m), e3 = __expf(s[h][3][r] - m);
      float sum = e0 + e1 + e2 + e3;
      #pragma unroll
      for (int off = 8; off > 0; off >>= 1) sum += __shfl_xor(sum, off, 16);
      float inv = 1.f / sum;
      const int row = quad * 4 + r;
      spw[row * 72 +      l16] = f2us(e0 * inv);
      spw[row * 72 + 16 + l16] = f2us(e1 * inv);
      spw[row * 72 + 32 + l16] = f2us(e2 * inv);
      spw[row * 72 + 48 + l16] = f2us(e3 * inv);
    }
    short8 pa[2];
    pa[0] = *reinterpret_cast<const short8*>(&spw[l16 * 72 + quad * 8]);
    pa[1] = *reinterpret_cast<const short8*>(&spw[l16 * 72 + 32 + quad * 8]);
    #pragma unroll
    for (int nt = 0; nt < 2; ++nt) {
      const int c0 = d0 + nt * 16;
      f32x4 acc = {0.f, 0.f, 0.f, 0.f};
      #pragma unroll
      for (int ks = 0; ks < 2; ++ks) {
        short8 vb = *reinterpret_cast<const short8*>(&svT[(c0 + l16) * 72 + ks * 32 + quad * 8]);
        acc = __builtin_amdgcn_mfma_f32_16x16x32_bf16(pa[ks], vb, acc, 0, 0, 0);
      }
      #pragma unroll
      for (int r = 0; r < 4; ++r)
        syb[(t0 + quad * 4 + r) * 104 + c0 + l16] = f2us(acc[r]);
    }
  }

  // ---- proj: N=96 (6 tiles), K=96 (3 steps); prefetched residuals + depth-2 B ring ----
  {
    short8 aa[3];
    #pragma unroll
    for (int ks = 0; ks < 3; ++ks)
      aa[ks] = *reinterpret_cast<const short8*>(&syb[(t0 + l16) * 104 + quad * 8 + ks * 32]);

    size_t tokr[4]; bool tval[4];
    #pragma unroll
    for (int r = 0; r < 4; ++r) {
      const int t = t0 + quad * 4 + r;
      tval[r] = (t < NT);
      int rr = t / WSZ + SSH; if (rr >= WSZ) rr -= WSZ;
      int qq = t % WSZ + SSH; if (qq >= WSZ) qq -= WSZ;
      tokr[r] = (size_t)bb * NL + (size_t)(hbase + rr) * NWW + (wbase + qq);
    }
    float xv[6][4];
    #pragma unroll
    for (int nt = 0; nt < 6; ++nt)
      #pragma unroll
      for (int r = 0; r < 4; ++r)
        xv[nt][r] = tval[r] ? x[tokr[r] * NC + nt * 16 + l16] : 0.f;

    short8 pbr[2][3];
    #pragma unroll
    for (int ks = 0; ks < 3; ++ks)
      pbr[0][ks] = *reinterpret_cast<const short8*>(
          projwb + (size_t)l16 * NC + quad * 8 + ks * 32);
    #pragma unroll
    for (int nt = 0; nt < 6; ++nt) {
      const int n0 = nt * 16;
      const float pb = proj_b[n0 + l16];
      short8 b0 = pbr[nt & 1][0], b1 = pbr[nt & 1][1], b2 = pbr[nt & 1][2];
      if (nt + 1 < 6) {
        #pragma unroll
        for (int ks = 0; ks < 3; ++ks)
          pbr[(nt + 1) & 1][ks] = *reinterpret_cast<const short8*>(
              projwb + (size_t)((nt + 1) * 16 + l16) * NC + quad * 8 + ks * 32);
      }
      f32x4 acc = {0.f, 0.f, 0.f, 0.f};
      acc = __builtin_amdgcn_mfma_f32_16x16x32_bf16(aa[0], b0, acc, 0, 0, 0);
      acc = __builtin_amdgcn_mfma_f32_16x16x32_bf16(aa[1], b1, acc, 0, 0, 0);
      acc = __builtin_amdgcn_mfma_f32_16x16x32_bf16(aa[2], b2, acc, 0, 0, 0);
      #pragma unroll
      for (int r = 0; r < 4; ++r) {
        if (tval[r])
          x1[tokr[r] * NC + n0 + l16] = xv[nt][r] + acc[r] + pb;
      }
    }
  }
}

// ---- K4 helper: literal pair pack (softplus, bf16, interleaved cols) ----
__device__ __forceinline__ short8 lit_pack(f32x4 p, f32x4 pbv) {
  union { short8 s; u32 w[4]; } u;
  #pragma unroll
  for (int r = 0; r < 4; ++r) {
    const float a  = p[r] + pbv[r];
    const float sp = fmaxf(a, 0.f) + __logf(1.f + __expf(-fabsf(a)));
    const u16 lo = f2us(fmaxf(a - sp, LOG_EPS));
    const u16 hi = f2us(fmaxf(-sp,    LOG_EPS));
    u.w[r] = (u32)lo | ((u32)hi << 16);
  }
  return u.s;
}

__device__ __forceinline__ float sum4_(float4 v) { return (v.x + v.y) + (v.z + v.w); }

// ---------------- K4: fused register-resident TM-FFN; 16 tokens/block, 1 wave, NO barriers ----------------
// Round-3 dataflow (swapped pin MFMA -> in-lane softplus pack -> clause MFMAs,
// zero shuffles / zero barriers) but RIGHT-SIZED: 1 wave per block, 16 tokens,
// NO prefetch rings -> ~110 loop-live VGPRs (round-3's ~220 spilled to scratch
// at VGPR_Count=128 -> 35us/wave pathology). Latency is hidden by TLP instead:
// grid = 3136 one-wave blocks (12.25/CU), LDS 4,352 B/block, launch_bounds(64,3)
// caps VGPR at ~170 (3 waves/SIMD resident).
// Per tile ks: load pin A-frags + mask B-frags directly (L2-resident constants),
// 3 pin MFMA -> lit_pack -> 8 clause MFMA into cacc[8].
__global__ __launch_bounds__(64, 3) void k4_ffn(const float* __restrict__ x1,
                                              const float* __restrict__ g2,
                                              const float* __restrict__ b2,
                                              const float* __restrict__ gf,
                                              const float* __restrict__ bf,
                                              const u16* __restrict__ pinwb,
                                              const float* __restrict__ pin_b,
                                              const u16* __restrict__ maskb,
                                              const u16* __restrict__ tmoT,
                                              const float* __restrict__ gate,
                                              float* __restrict__ out) {
  __shared__ __align__(16) u16 claT[16 * 136];   // 4,352 B; wave-private (1-wave block)
  const int lane = threadIdx.x & 63;
  const int l16  = lane & 15;
  const int quad = lane >> 4;
  const size_t tok0 = (size_t)blockIdx.x * 16;

  // ---- double-LN directly into zb B-frags ----
  // lane (l16,quad) owns token tok0+l16, channels {k*32+quad*8 .. +7}, k=0..2.
  // 96-ch reduction = 2-step shfl_xor(16,32) butterfly across the 4 quads.
  // gamma/beta loads are INLINE (short live ranges; round-3 hoisted 96 VGPRs of
  // them which contributed to the spill).
  short8 zb[3];
  {
    const float* xp = x1 + (tok0 + l16) * NC + quad * 8;
    float4 va[3], vb[3];
    float sum = 0.f;
    #pragma unroll
    for (int k = 0; k < 3; ++k) {
      va[k] = *reinterpret_cast<const float4*>(xp + k * 32);
      vb[k] = *reinterpret_cast<const float4*>(xp + k * 32 + 4);
      sum += sum4_(va[k]) + sum4_(vb[k]);
    }
    sum += __shfl_xor(sum, 16); sum += __shfl_xor(sum, 32);
    const float mean = sum * (1.f / 96.f);
    float ssq = 0.f;
    #pragma unroll
    for (int k = 0; k < 3; ++k) {
      float d;
      d = va[k].x - mean; ssq += d * d;  d = va[k].y - mean; ssq += d * d;
      d = va[k].z - mean; ssq += d * d;  d = va[k].w - mean; ssq += d * d;
      d = vb[k].x - mean; ssq += d * d;  d = vb[k].y - mean; ssq += d * d;
      d = vb[k].z - mean; ssq += d * d;  d = vb[k].w - mean; ssq += d * d;
    }
    ssq += __shfl_xor(ssq, 16); ssq += __shfl_xor(ssq, 32);
    const float rstd = rsqrtf(ssq * (1.f / 96.f) + 1e-5f);
    float sum2 = 0.f;
    #pragma unroll
    for (int k = 0; k < 3; ++k) {
      const int c = k * 32 + quad * 8;
      const float4 ga = *reinterpret_cast<const float4*>(g2 + c);
      const float4 gb = *reinterpret_cast<const float4*>(g2 + c + 4);
      const float4 ba = *reinterpret_cast<const float4*>(b2 + c);
      const float4 bb = *reinterpret_cast<const float4*>(b2 + c + 4);
      va[k].x = (va[k].x - mean) * rstd * ga.x + ba.x; sum2 += va[k].x;
      va[k].y = (va[k].y - mean) * rstd * ga.y + ba.y; sum2 += va[k].y;
      va[k].z = (va[k].z - mean) * rstd * ga.z + ba.z; sum2 += va[k].z;
      va[k].w = (va[k].w - mean) * rstd * ga.w + ba.w; sum2 += va[k].w;
      vb[k].x = (vb[k].x - mean) * rstd * gb.x + bb.x; sum2 += vb[k].x;
      vb[k].y = (vb[k].y - mean) * rstd * gb.y + bb.y; sum2 += vb[k].y;
      vb[k].z = (vb[k].z - mean) * rstd * gb.z + bb.z; sum2 += vb[k].z;
      vb[k].w = (vb[k].w - mean) * rstd * gb.w + bb.w; sum2 += vb[k].w;
    }
    sum2 += __shfl_xor(sum2, 16); sum2 += __shfl_xor(sum2, 32);
    const float mean2 = sum2 * (1.f / 96.f);
    float ssq2 = 0.f;
    #pragma unroll
    for (int k = 0; k < 3; ++k) {
      float d;
      d = va[k].x - mean2; ssq2 += d * d;  d = va[k].y - mean2; ssq2 += d * d;
      d = va[k].z - mean2; ssq2 += d * d;  d = va[k].w - mean2; ssq2 += d * d;
      d = vb[k].x - mean2; ssq2 += d * d;  d = vb[k].y - mean2; ssq2 += d * d;
      d = vb[k].z - mean2; ssq2 += d * d;  d = vb[k].w - mean2; ssq2 += d * d;
    }
    ssq2 += __shfl_xor(ssq2, 16); ssq2 += __shfl_xor(ssq2, 32);
    const float rstd2 = rsqrtf(ssq2 * (1.f / 96.f) + 1e-5f);
    #pragma unroll
    for (int k = 0; k < 3; ++k) {
      const int c = k * 32 + quad * 8;
      const float4 ga = *reinterpret_cast<const float4*>(gf + c);
      const float4 gb = *reinterpret_cast<const float4*>(gf + c + 4);
      const float4 ba = *reinterpret_cast<const float4*>(bf + c);
      const float4 bb = *reinterpret_cast<const float4*>(bf + c + 4);
      const float z0 = (va[k].x - mean2) * rstd2 * ga.x + ba.x;
      const float z1 = (va[k].y - mean2) * rstd2 * ga.y + ba.y;
      const float z2 = (va[k].z - mean2) * rstd2 * ga.z + ba.z;
      const float z3 = (va[k].w - mean2) * rstd2 * ga.w + ba.w;
      const float z4 = (vb[k].x - mean2) * rstd2 * gb.x + bb.x;
      const float z5 = (vb[k].y - mean2) * rstd2 * gb.y + bb.y;
      const float z6 = (vb[k].z - mean2) * rstd2 * gb.z + bb.z;
      const float z7 = (vb[k].w - mean2) * rstd2 * gb.w + bb.w;
      union { short8 s; u32 w[4]; } uz;
      uz.w[0] = (u32)f2us(z0) | ((u32)f2us(z1) << 16);
      uz.w[1] = (u32)f2us(z2) | ((u32)f2us(z3) << 16);
      uz.w[2] = (u32)f2us(z4) | ((u32)f2us(z5) << 16);
      uz.w[3] = (u32)f2us(z6) | ((u32)f2us(z7) << 16);
      zb[k] = uz.s;
    }
  }

  // ---- fused pin -> softplus -> clause loop over 24 hidden tiles; no rings ----
  f32x4 cacc[8];
  {
    const f32x4 z4 = {0.f, 0.f, 0.f, 0.f};
    #pragma unroll
    for (int ct = 0; ct < 8; ++ct) cacc[ct] = z4;
  }
  #pragma unroll 2
  for (int ks = 0; ks < 24; ++ks) {
    // mask B-frags for this k-slice (issue first: consumed last)
    short8 mb0 = *reinterpret_cast<const short8*>(maskb + (size_t)(0 * 16 + l16) * NLIT + ks * 32 + quad * 8);
    short8 mb1 = *reinterpret_cast<const short8*>(maskb + (size_t)(1 * 16 + l16) * NLIT + ks * 32 + quad * 8);
    short8 mb2 = *reinterpret_cast<const short8*>(maskb + (size_t)(2 * 16 + l16) * NLIT + ks * 32 + quad * 8);
    short8 mb3 = *reinterpret_cast<const short8*>(maskb + (size_t)(3 * 16 + l16) * NLIT + ks * 32 + quad * 8);
    short8 mb4 = *reinterpret_cast<const short8*>(maskb + (size_t)(4 * 16 + l16) * NLIT + ks * 32 + quad * 8);
    short8 mb5 = *reinterpret_cast<const short8*>(maskb + (size_t)(5 * 16 + l16) * NLIT + ks * 32 + quad * 8);
    short8 mb6 = *reinterpret_cast<const short8*>(maskb + (size_t)(6 * 16 + l16) * NLIT + ks * 32 + quad * 8);
    short8 mb7 = *reinterpret_cast<const short8*>(maskb + (size_t)(7 * 16 + l16) * NLIT + ks * 32 + quad * 8);
    // pin A-frags (hidden rows ks*16+l16, channel chunks) + bias
    const u16* pp = pinwb + (size_t)(ks * 16 + l16) * NC + quad * 8;
    short8 pa0 = *reinterpret_cast<const short8*>(pp);
    short8 pa1 = *reinterpret_cast<const short8*>(pp + 32);
    short8 pa2 = *reinterpret_cast<const short8*>(pp + 64);
    f32x4 pbv = *reinterpret_cast<const f32x4*>(pin_b + ks * 16 + quad * 4);
    // swapped pin gemm: C col=l16=token, row=quad*4+r=hidden -> lit_pack output
    // IS this lane's clause A-frag (cols ks*32+quad*8, token l16).
    f32x4 p = {0.f, 0.f, 0.f, 0.f};
    p = __builtin_amdgcn_mfma_f32_16x16x32_bf16(pa0, zb[0], p, 0, 0, 0);
    p = __builtin_amdgcn_mfma_f32_16x16x32_bf16(pa1, zb[1], p, 0, 0, 0);
    p = __builtin_amdgcn_mfma_f32_16x16x32_bf16(pa2, zb[2], p, 0, 0, 0);
    const short8 lf = lit_pack(p, pbv);
    cacc[0] = __builtin_amdgcn_mfma_f32_16x16x32_bf16(lf, mb0, cacc[0], 0, 0, 0);
    cacc[1] = __builtin_amdgcn_mfma_f32_16x16x32_bf16(lf, mb1, cacc[1], 0, 0, 0);
    cacc[2] = __builtin_amdgcn_mfma_f32_16x16x32_bf16(lf, mb2, cacc[2], 0, 0, 0);
    cacc[3] = __builtin_amdgcn_mfma_f32_16x16x32_bf16(lf, mb3, cacc[3], 0, 0, 0);
    cacc[4] = __builtin_amdgcn_mfma_f32_16x16x32_bf16(lf, mb4, cacc[4], 0, 0, 0);
    cacc[5] = __builtin_amdgcn_mfma_f32_16x16x32_bf16(lf, mb5, cacc[5], 0, 0, 0);
    cacc[6] = __builtin_amdgcn_mfma_f32_16x16x32_bf16(lf, mb6, cacc[6], 0, 0, 0);
    cacc[7] = __builtin_amdgcn_mfma_f32_16x16x32_bf16(lf, mb7, cacc[7], 0, 0, 0);
  }

  // ---- clauses = exp(cacc) -> claT (same-wave RAW via lgkmcnt, no barrier) ----
  #pragma unroll
  for (int ct = 0; ct < 8; ++ct)
    #pragma unroll
    for (int r = 0; r < 4; ++r)
      claT[(quad * 4 + r) * 136 + ct * 16 + l16] = f2us(__expf(cacc[ct][r]));

  // ---- residual prefetch (overlaps claT round-trip + logits B loads) ----
  float xr[6][4];
  #pragma unroll
  for (int nt = 0; nt < 6; ++nt)
    #pragma unroll
    for (int r = 0; r < 4; ++r)
      xr[nt][r] = x1[(tok0 + quad * 4 + r) * NC + nt * 16 + l16];

  // ---- logits = cla @ tm_out + fused blend epilogue ----
  short8 caf[4];
  #pragma unroll
  for (int ksl = 0; ksl < 4; ++ksl)
    caf[ksl] = *reinterpret_cast<const short8*>(
        &claT[l16 * 136 + ksl * 32 + quad * 8]);
  const float gv = sigmoidf_(gate[0]);
  #pragma unroll
  for (int nt = 0; nt < 6; ++nt) {
    short8 btm[4];
    #pragma unroll
    for (int ksl = 0; ksl < 4; ++ksl)
      btm[ksl] = *reinterpret_cast<const short8*>(
          tmoT + (size_t)(nt * 16 + l16) * NCL_ + ksl * 32 + quad * 8);
    f32x4 o0 = {0.f, 0.f, 0.f, 0.f};
    #pragma unroll
    for (int ksl = 0; ksl < 4; ++ksl)
      o0 = __builtin_amdgcn_mfma_f32_16x16x32_bf16(caf[ksl], btm[ksl], o0, 0, 0, 0);
    const int c = nt * 16 + l16;
    #pragma unroll
    for (int r = 0; r < 4; ++r) {
      const float lg = o0[r];
      out[(tok0 + quad * 4 + r) * NC + c] = xr[nt][r] + gv * lg + (1.f - gv) * sigmoidf_(lg);
    }
  }
}

extern "C" void kernel_launch(void* const* d_in, const int* in_sizes, int n_in,
                              void* d_out, int out_size, void* d_ws, size_t ws_size,
                              hipStream_t stream) {
  (void)in_sizes; (void)n_in; (void)out_size; (void)ws_size;
  const float* x      = (const float*)d_in[0];
  const float* n1g    = (const float*)d_in[1];
  const float* n1b    = (const float*)d_in[2];
  const float* qkv_w  = (const float*)d_in[3];
  const float* qkv_b  = (const float*)d_in[4];
  const float* proj_w = (const float*)d_in[5];
  const float* proj_b = (const float*)d_in[6];
  const float* n2g    = (const float*)d_in[7];
  const float* n2b    = (const float*)d_in[8];
  const float* fng    = (const float*)d_in[9];
  const float* fnb    = (const float*)d_in[10];
  const float* pin_w  = (const float*)d_in[11];
  const float* pin_b  = (const float*)d_in[12];
  const float* tm_inc = (const float*)d_in[13];
  const float* tm_out = (const float*)d_in[14];
  const float* gate   = (const float*)d_in[15];

  float* x1 = (float*)d_ws;                         // NTOK*96 f32
  u16* maskb = (u16*)(x1 + (size_t)NTOK * NC);      // 128*768 bf16 (col-interleaved)
  u16* pinwb = maskb + NCL_ * NLIT;                 // 384*96 bf16
  u16* tmoT  = pinwb + HID_ * NC;                   // 96*128 bf16
  u16* qkvwb = tmoT + NC * NCL_;                    // 288*96 bf16
  u16* projwb= qkvwb + 3 * NC * NC;                 // 96*96 bf16

  hipLaunchKernelGGL(k0_prep, dim3(384), dim3(256), 0, stream,
                     tm_inc, pin_w, tm_out, qkv_w, proj_w, maskb, pinwb, tmoT, qkvwb, projwb);
  hipLaunchKernelGGL(k2_attn, dim3(NWIN), dim3(256), 0, stream,
                     x, n1g, n1b, qkvwb, qkv_b, projwb, proj_b, x1);
  hipLaunchKernelGGL(k4_ffn, dim3(NTOK / 16), dim3(64), 0, stream,
                     x1, n2g, n2b, fng, fnb, pinwb, pin_b, maskb, tmoT, gate, (float*)d_out);
}